// Round 1
// baseline (377.685 us; speedup 1.0000x reference)
//
#include <hip/hip_runtime.h>
#include <stdint.h>

typedef unsigned int u32;
typedef unsigned long long u64;

#define F_UPPER 0.4f
#define F_LOWER 0.1f
#define MAX_POS 2048

struct State {
  double sum_pos_ce;
  double sum_neg_ce;
  double bbox_sum;
  int num_pos;
  int num_neg;
  int n_pairs;
  int select_all;
  int sel_k;
  int _pad;
  u64 prefix;
  u64 thresh;
};

// ---------- helpers ----------

__device__ __forceinline__ float iou_fn(const float4 a, const float4 b) {
#pragma clang fp contract(off)
  float a1 = (a.z - a.x + 1.0f) * (a.w - a.y + 1.0f);
  float a2 = (b.z - b.x + 1.0f) * (b.w - b.y + 1.0f);
  float iw = fminf(a.z, b.z) - fmaxf(a.x, b.x) + 1.0f;
  iw = fmaxf(iw, 0.0f);
  float ih = fminf(a.w, b.w) - fmaxf(a.y, b.y) + 1.0f;
  ih = fmaxf(ih, 0.0f);
  float inter = iw * ih;
  return inter / (a1 + a2 - inter);
}

__device__ __forceinline__ float sl1(float d) {
#pragma clang fp contract(off)
  float ad = fabsf(d);
  return (ad < 0.01f) ? (50.0f * d * d) : (ad - 0.005f);
}

__device__ __forceinline__ u32 rotl(u32 x, int d) { return (x << d) | (x >> (32 - d)); }

// JAX threefry2x32, key = (0, 42) from jax.random.key(42); counts = iota(L) split in halves.
__device__ u32 threefry_bits(u32 i, u32 H) {
  u32 x0, x1; bool hi;
  if (i < H) { x0 = i;     x1 = i + H; hi = false; }
  else       { x0 = i - H; x1 = i;     hi = true;  }
  const u32 ks0 = 0u, ks1 = 42u;
  const u32 ks2 = ks0 ^ ks1 ^ 0x1BD11BDAu;
  x0 += ks0; x1 += ks1;
#define RND(r) { x0 += x1; x1 = rotl(x1, r); x1 ^= x0; }
  RND(13) RND(15) RND(26) RND(6)   x0 += ks1; x1 += ks2 + 1u;
  RND(17) RND(29) RND(16) RND(24)  x0 += ks2; x1 += ks0 + 2u;
  RND(13) RND(15) RND(26) RND(6)   x0 += ks0; x1 += ks1 + 3u;
  RND(17) RND(29) RND(16) RND(24)  x0 += ks1; x1 += ks2 + 4u;
  RND(13) RND(15) RND(26) RND(6)   x0 += ks2; x1 += ks0 + 5u;
#undef RND
  return hi ? x1 : x0;
}

// ---------- kernels ----------

__global__ void k_init(State* st, u64* gkey, int M, int* scat, int L, u32* hist, int nhist) {
  int i = blockIdx.x * blockDim.x + threadIdx.x;
  if (i == 0) {
    st->sum_pos_ce = 0.0; st->sum_neg_ce = 0.0; st->bbox_sum = 0.0;
    st->num_pos = 0; st->num_neg = 0; st->n_pairs = 0;
    st->select_all = 0; st->sel_k = 0; st->prefix = 0ull; st->thresh = 0ull;
  }
  if (i < M) gkey[i] = 0ull;
  if (i < L) scat[i] = -1;
  if (i < nhist) hist[i] = 0u;
}

__global__ void k_roi(const float* __restrict__ rois, const float* __restrict__ scores,
                      const float* __restrict__ deltas, int L, int C,
                      float4* __restrict__ pred, float* __restrict__ lse) {
  int i = blockIdx.x * blockDim.x + threadIdx.x;
  if (i >= L) return;
  const float* sr = scores + (size_t)i * C;
  float mx = sr[0]; int mi = 0;
  for (int j = 1; j < C; ++j) { float v = sr[j]; if (v > mx) { mx = v; mi = j; } }
  float s = 0.0f;
  for (int j = 0; j < C; ++j) s += expf(sr[j] - mx);
  lse[i] = mx + logf(s);
  const float* r = rois + (size_t)i * 5;
  const float* d = deltas + (size_t)i * 4 * C + 4 * mi;
  float4 p;
  p.x = r[1] + d[0]; p.y = r[2] + d[1]; p.z = r[3] + d[2]; p.w = r[4] + d[3];
  pred[i] = p;
}

__global__ void __launch_bounds__(256) k_iou(const float4* __restrict__ pred,
    const float4* __restrict__ gt, int L, int M,
    float* __restrict__ bestp, int* __restrict__ idxp, u64* __restrict__ gkey) {
  __shared__ float4 sp[256];
  __shared__ float4 sg[512];
  int tid = threadIdx.x;
  int base = blockIdx.x * 256;
  int nload = L - base; if (nload > 256) nload = 256;
  int Mc = (M < 512) ? M : 512;
  if (tid < nload) sp[tid] = pred[base + tid];
  for (int j = tid; j < Mc; j += 256) sg[j] = gt[j];
  __syncthreads();
  // phase A: per-pred row max / first-argmax
  if (tid < nload) {
    float4 p = sp[tid];
    float best = -1.0f; int bi = 0;
    for (int j = 0; j < Mc; ++j) {
      float v = iou_fn(p, sg[j]);
      if (v > best) { best = v; bi = j; }
    }
    bestp[base + tid] = best;
    idxp[base + tid] = bi;
  }
  // phase B: per-gt column max with lowest-index tie-break, merged globally via atomicMax
  for (int g = tid; g < Mc; g += 256) {
    float4 q = sg[g];
    u64 key = 0ull;
    for (int p = 0; p < nload; ++p) {
      float v = iou_fn(sp[p], q);
      u64 k = ((u64)__float_as_uint(v) << 32) | (u32)(0xFFFFFFFFu - (u32)(base + p));
      if (k > key) key = k;
    }
    atomicMax(&gkey[g], key);
  }
}

__global__ void k_scatter(const u64* __restrict__ gkey, int M, int* __restrict__ scat) {
  int g = blockIdx.x * blockDim.x + threadIdx.x;
  if (g >= M) return;
  u64 key = gkey[g];
  int p = (int)(0xFFFFFFFFu - (u32)(key & 0xFFFFFFFFull));
  atomicMax(&scat[p], g);  // duplicate idx_g: last (max g) wins, matching numpy sequential set
}

__global__ void k_match(const float* __restrict__ bestp, const int* __restrict__ idxp,
    const int* __restrict__ scat, const int* __restrict__ gt_cls,
    const float* __restrict__ scores, const float* __restrict__ lse,
    int L, int C, int* __restrict__ matches, u32* __restrict__ u23, State* st) {
  int i = blockIdx.x * blockDim.x + threadIdx.x;
  if (i >= L) return;
  float best = bestp[i];
  int m;
  if (best < F_LOWER) m = -2;
  else {
    int s = scat[i];
    m = (s >= 0) ? s : ((best >= F_UPPER) ? idxp[i] : -1);
  }
  matches[i] = m;
  if (m >= 0) {
    atomicAdd(&st->num_pos, 1);
    int lbl = gt_cls[m];
    float ce = lse[i] - scores[(size_t)i * C + lbl];
    atomicAdd(&st->sum_pos_ce, (double)ce);
  } else if (m == -2) {
    atomicAdd(&st->num_neg, 1);
  }
  u23[i] = threefry_bits((u32)i, (u32)(L >> 1)) >> 9;
}

__global__ void __launch_bounds__(256) k_compact(const int* __restrict__ matches,
    const float4* __restrict__ pred, const float4* __restrict__ gt, int L,
    float4* __restrict__ pp, float4* __restrict__ gp, State* st) {
  __shared__ int wsum[4];
  __shared__ int srun_s;
  int tid = threadIdx.x, lane = tid & 63, wid = tid >> 6;
  if (tid == 0) srun_s = 0;
  __syncthreads();
  const int VPT = 8, CHUNK = 256 * VPT;
  for (int base = 0; base < L; base += CHUNK) {
    int i0 = base + tid * VPT;
    int m[VPT];
#pragma unroll
    for (int r = 0; r < VPT; ++r) m[r] = (i0 + r < L) ? matches[i0 + r] : -1;
    int c = 0;
#pragma unroll
    for (int r = 0; r < VPT; ++r) c += (m[r] >= 0) ? 1 : 0;
    int incl = c;
#pragma unroll
    for (int off = 1; off < 64; off <<= 1) {
      int v = __shfl_up(incl, off, 64);
      if (lane >= off) incl += v;
    }
    if (lane == 63) wsum[wid] = incl;
    __syncthreads();
    int wbase = 0;
    for (int w = 0; w < wid; ++w) wbase += wsum[w];
    int total = wsum[0] + wsum[1] + wsum[2] + wsum[3];
    int rank = srun_s + wbase + (incl - c);
#pragma unroll
    for (int r = 0; r < VPT; ++r) {
      if (m[r] >= 0) {
        if (rank < MAX_POS) { pp[rank] = pred[i0 + r]; gp[rank] = gt[m[r]]; }
        ++rank;
      }
    }
    __syncthreads();
    if (tid == 0) srun_s += total;
  }
  __syncthreads();
  if (tid == 0) st->n_pairs = (srun_s < MAX_POS) ? srun_s : MAX_POS;
}

__global__ void k_hist(const int* __restrict__ matches, const u32* __restrict__ u23,
                       int L, int pass, State* st, u32* __restrict__ hist) {
  if (st->select_all) return;
  int i = blockIdx.x * blockDim.x + threadIdx.x;
  if (i >= L) return;
  if (matches[i] != -2) return;
  u64 key = ((u64)u23[i] << 16) | (u32)i;
  int shift = 26 - 13 * pass;
  if (pass > 0 && (key >> (shift + 13)) != st->prefix) return;
  atomicAdd(&hist[(u32)((key >> shift) & 0x1FFFull)], 1u);
}

__global__ void __launch_bounds__(1024) k_scan(State* st, const u32* __restrict__ hist, int pass) {
  if (st->select_all) return;
  int tid = threadIdx.x;
  int k = (pass == 0) ? st->num_pos : st->sel_k;  // bg_num = round(num_pos*1.0) = num_pos
  if (pass == 0 && k >= st->num_neg) {
    if (tid == 0) { st->select_all = 1; st->thresh = ~0ull; }
    return;
  }
  int loc[8]; int tsum = 0;
#pragma unroll
  for (int r = 0; r < 8; ++r) { loc[r] = (int)hist[tid * 8 + r]; tsum += loc[r]; }
  __shared__ int sc[1024];
  sc[tid] = tsum;
  __syncthreads();
  for (int off = 1; off < 1024; off <<= 1) {
    int v = (tid >= off) ? sc[tid - off] : 0;
    __syncthreads();
    sc[tid] += v;
    __syncthreads();
  }
  int incl = sc[tid], excl = incl - tsum;
  if (k >= excl && k < incl) {
    int kk = k - excl; int d = 0;
#pragma unroll
    for (int r = 0; r < 8; ++r) {
      if (kk < loc[r]) { d = tid * 8 + r; break; }
      kk -= loc[r];
    }
    u64 np = (pass == 0) ? (u64)d : ((st->prefix << 13) | (u64)d);
    st->prefix = np;
    st->sel_k = kk;
    if (pass == 2) st->thresh = np;  // exact 39-bit key with rank == bg_num; select key < thresh
  }
}

__global__ void k_negsum(const int* __restrict__ matches, const u32* __restrict__ u23,
    const float* __restrict__ scores, const float* __restrict__ lse,
    int L, int C, State* st) {
  int i = blockIdx.x * blockDim.x + threadIdx.x;
  if (i >= L) return;
  if (matches[i] != -2) return;
  u64 key = ((u64)u23[i] << 16) | (u32)i;
  if (key < st->thresh) {
    float ce = lse[i] - scores[(size_t)i * C + (C - 1)];  // BACKGROUND = C-1 = 20
    atomicAdd(&st->sum_neg_ce, (double)ce);
  }
}

__global__ void __launch_bounds__(256) k_pairs(const float4* __restrict__ pp,
    const float4* __restrict__ gp, State* st) {
  __shared__ float4 sj[128];
  int tid = threadIdx.x;
  int n = st->n_pairs;
  int jbase = blockIdx.y * 128;
  if (tid < 128) {
    int j = jbase + tid;
    sj[tid] = (j < n) ? pp[j] : make_float4(0.f, 0.f, 0.f, 0.f);
  }
  __syncthreads();
  int i = blockIdx.x * 256 + tid;
  double acc = 0.0;
  if (i < n) {
    float4 g = gp[i];
    int jend = n - jbase; if (jend > 128) jend = 128;
    for (int j = 0; j < jend; ++j) {
      float4 p = sj[j];
      acc += (double)sl1(p.x - g.x);
      acc += (double)sl1(p.y - g.y);
      acc += (double)sl1(p.z - g.z);
      acc += (double)sl1(p.w - g.w);
    }
  }
  for (int off = 32; off > 0; off >>= 1) acc += __shfl_down(acc, off, 64);
  __shared__ double wacc[4];
  int lane = tid & 63, wid = tid >> 6;
  if (lane == 0) wacc[wid] = acc;
  __syncthreads();
  if (tid == 0) atomicAdd(&st->bbox_sum, wacc[0] + wacc[1] + wacc[2] + wacc[3]);
}

__global__ void k_final(State* st, float* out) {
  int np = st->num_pos, nn = st->num_neg;
  int nsel = (np < nn) ? np : nn;  // min(bg_num, num_neg)
  double wsum = (double)(np + nsel);
  out[0] = (float)((st->sum_pos_ce + st->sum_neg_ce) / wsum);
  out[1] = (float)st->bbox_sum;
}

// ---------- launch ----------

extern "C" void kernel_launch(void* const* d_in, const int* in_sizes, int n_in,
                              void* d_out, int out_size, void* d_ws, size_t ws_size,
                              hipStream_t stream) {
  const float* rois   = (const float*)d_in[0];
  const float* scores = (const float*)d_in[1];
  const float* deltas = (const float*)d_in[2];
  const float* gtb    = (const float*)d_in[3];
  const int*   gtc    = (const int*)d_in[4];
  int L = in_sizes[0] / 5;
  int C = in_sizes[1] / L;
  int M = in_sizes[4];

  char* w = (char*)d_ws;
  State* st   = (State*)w;    w += 256;
  float4* pred = (float4*)w;  w += (size_t)L * 16;
  float* lse   = (float*)w;   w += (size_t)L * 4;
  float* bestp = (float*)w;   w += (size_t)L * 4;
  int* idxp    = (int*)w;     w += (size_t)L * 4;
  int* scat    = (int*)w;     w += (size_t)L * 4;
  int* matches = (int*)w;     w += (size_t)L * 4;
  u32* u23     = (u32*)w;     w += (size_t)L * 4;
  u64* gkey    = (u64*)w;     w += (size_t)M * 8;
  float4* pp   = (float4*)w;  w += (size_t)MAX_POS * 16;
  float4* gp   = (float4*)w;  w += (size_t)MAX_POS * 16;
  u32* hist    = (u32*)w;     w += 3 * 8192 * 4;

  int nb = (L + 255) / 256;
  int nhist = 3 * 8192;
  int initN = L > nhist ? L : nhist;
  if (M > initN) initN = M;

  k_init<<<(initN + 255) / 256, 256, 0, stream>>>(st, gkey, M, scat, L, hist, nhist);
  k_roi<<<nb, 256, 0, stream>>>(rois, scores, deltas, L, C, pred, lse);
  k_iou<<<nb, 256, 0, stream>>>(pred, (const float4*)gtb, L, M, bestp, idxp, gkey);
  k_scatter<<<(M + 255) / 256, 256, 0, stream>>>(gkey, M, scat);
  k_match<<<nb, 256, 0, stream>>>(bestp, idxp, scat, gtc, scores, lse, L, C, matches, u23, st);
  k_compact<<<1, 256, 0, stream>>>(matches, pred, (const float4*)gtb, L, pp, gp, st);
  for (int p = 0; p < 3; ++p) {
    k_hist<<<nb, 256, 0, stream>>>(matches, u23, L, p, st, hist + p * 8192);
    k_scan<<<1, 1024, 0, stream>>>(st, hist + p * 8192, p);
  }
  k_negsum<<<nb, 256, 0, stream>>>(matches, u23, scores, lse, L, C, st);
  dim3 pg((MAX_POS + 255) / 256, 16);
  k_pairs<<<pg, 256, 0, stream>>>(pp, gp, st);
  k_final<<<1, 1, 0, stream>>>(st, (float*)d_out);
}

// Round 2
// 213.498 us; speedup vs baseline: 1.7690x; 1.7690x over previous
//
#include <hip/hip_runtime.h>
#include <stdint.h>

typedef unsigned int u32;
typedef unsigned long long u64;

#define F_UPPER 0.4f
#define F_LOWER 0.1f
#define MAX_POS 2048

struct State {
  double sum_pos_ce;
  double sum_neg_ce;
  double bbox_sum;
  int num_pos;
  int num_neg;
  int select_all;
  int sel_k;
  u64 prefix;
  u64 thresh;
};

// ---------- helpers ----------

__device__ __forceinline__ float area_fn(const float4 a) {
#pragma clang fp contract(off)
  return (a.z - a.x + 1.0f) * (a.w - a.y + 1.0f);
}

// IoU with precomputed areas; op order identical to reference (bit-exact f32).
__device__ __forceinline__ float iou_fn(const float4 a, const float4 b, float a1, float a2) {
#pragma clang fp contract(off)
  float iw = fminf(a.z, b.z) - fmaxf(a.x, b.x) + 1.0f;
  iw = fmaxf(iw, 0.0f);
  float ih = fminf(a.w, b.w) - fmaxf(a.y, b.y) + 1.0f;
  ih = fmaxf(ih, 0.0f);
  float inter = iw * ih;
  return inter / (a1 + a2 - inter);
}

__device__ __forceinline__ float sl1(float d) {
#pragma clang fp contract(off)
  float ad = fabsf(d);
  return (ad < 0.01f) ? (50.0f * d * d) : (ad - 0.005f);
}

__device__ __forceinline__ u32 rotl(u32 x, int d) { return (x << d) | (x >> (32 - d)); }

// JAX threefry2x32, key = (0, 42); counts = iota(L) split in halves.
__device__ u32 threefry_bits(u32 i, u32 H) {
  u32 x0, x1; bool hi;
  if (i < H) { x0 = i;     x1 = i + H; hi = false; }
  else       { x0 = i - H; x1 = i;     hi = true;  }
  const u32 ks0 = 0u, ks1 = 42u;
  const u32 ks2 = ks0 ^ ks1 ^ 0x1BD11BDAu;
  x0 += ks0; x1 += ks1;
#define RND(r) { x0 += x1; x1 = rotl(x1, r); x1 ^= x0; }
  RND(13) RND(15) RND(26) RND(6)   x0 += ks1; x1 += ks2 + 1u;
  RND(17) RND(29) RND(16) RND(24)  x0 += ks2; x1 += ks0 + 2u;
  RND(13) RND(15) RND(26) RND(6)   x0 += ks0; x1 += ks1 + 3u;
  RND(17) RND(29) RND(16) RND(24)  x0 += ks1; x1 += ks2 + 4u;
  RND(13) RND(15) RND(26) RND(6)   x0 += ks2; x1 += ks0 + 5u;
#undef RND
  return hi ? x1 : x0;
}

// ---------- kernels ----------

__global__ void k_init(State* st, u64* gkey, int M, int* scat, u64* rowkey, int L,
                       u32* hist, int nhist) {
  int i = blockIdx.x * blockDim.x + threadIdx.x;
  if (i == 0) {
    st->sum_pos_ce = 0.0; st->sum_neg_ce = 0.0; st->bbox_sum = 0.0;
    st->num_pos = 0; st->num_neg = 0;
    st->select_all = 0; st->sel_k = 0; st->prefix = 0ull; st->thresh = 0ull;
  }
  if (i < M) gkey[i] = 0ull;
  if (i < L) { scat[i] = -1; rowkey[i] = 0ull; }
  if (i < nhist) hist[i] = 0u;
}

// Per-ROI: argmax score, log-sum-exp, pred box. Coalesced via LDS staging.
__global__ void __launch_bounds__(256) k_roi(const float* __restrict__ rois,
    const float* __restrict__ scores, const float* __restrict__ deltas, int L, int C,
    float4* __restrict__ pred, float* __restrict__ lse) {
  __shared__ float ssc[256 * 21];
  __shared__ float sro[256 * 5];
  int tid = threadIdx.x;
  int base = blockIdx.x * 256;
  int nload = L - base; if (nload > 256) nload = 256;
  for (int k = tid; k < nload * C; k += 256) ssc[k] = scores[(size_t)base * C + k];
  for (int k = tid; k < nload * 5; k += 256) sro[k] = rois[(size_t)base * 5 + k];
  __syncthreads();
  if (tid >= nload) return;
  int i = base + tid;
  const float* sr = ssc + tid * C;
  float mx = sr[0]; int mi = 0;
  for (int j = 1; j < C; ++j) { float v = sr[j]; if (v > mx) { mx = v; mi = j; } }
  float s = 0.0f;
  for (int j = 0; j < C; ++j) s += expf(sr[j] - mx);
  lse[i] = mx + logf(s);
  // 16B-aligned gather: (84*i + 4*mi) floats is a multiple of 4 floats.
  float4 d = *(const float4*)(deltas + (size_t)i * 4 * C + 4 * mi);
  const float* r = sro + tid * 5;
  float4 p;
  p.x = r[1] + d.x; p.y = r[2] + d.y; p.z = r[3] + d.z; p.w = r[4] + d.w;
  pred[i] = p;
}

// Tile: 128 preds x 256 gts, 256 threads. grid = (L/128, M/256) = 1024 blocks -> 4 blocks/CU.
__global__ void __launch_bounds__(256) k_iou(const float4* __restrict__ pred,
    const float4* __restrict__ gt, int L, int M,
    u64* __restrict__ rowkey, u64* __restrict__ gkey) {
  __shared__ float4 sp[128];
  __shared__ float4 sg[256];
  __shared__ float sa[128];
  __shared__ float ga[256];
  int tid = threadIdx.x;
  int pbase = blockIdx.x * 128;
  int gbase = blockIdx.y * 256;
  int np = L - pbase; if (np > 128) np = 128;
  int ng = M - gbase; if (ng > 256) ng = 256;
  if (tid < np) { float4 v = pred[pbase + tid]; sp[tid] = v; sa[tid] = area_fn(v); }
  if (tid < ng) { float4 v = gt[gbase + tid];   sg[tid] = v; ga[tid] = area_fn(v); }
  __syncthreads();
  // Phase A: row (per-pred) max/first-argmax over this gt chunk; two threads per pred.
  {
    int p = tid & 127;
    int j0 = (tid >> 7) * 128;
    if (p < np) {
      float4 pb = sp[p]; float pa = sa[p];
      float best = -1.0f; int bj = 0;
      int jend = j0 + 128; if (jend > ng) jend = ng;
#pragma unroll 4
      for (int j = j0; j < jend; ++j) {
        float v = iou_fn(pb, sg[j], pa, ga[j]);
        if (v > best) { best = v; bj = gbase + j; }
      }
      if (j0 < ng) {
        u64 key = ((u64)__float_as_uint(best) << 32) | (u32)(0xFFFFFFFFu - (u32)bj);
        atomicMax(&rowkey[pbase + p], key);
      }
    }
  }
  // Phase B: column (per-gt) max with lowest-pred-index tie-break.
  if (tid < ng) {
    float4 gb = sg[tid]; float gba = ga[tid];
    float best = -1.0f; int bp = 0;
#pragma unroll 4
    for (int p = 0; p < np; ++p) {
      float v = iou_fn(sp[p], gb, sa[p], gba);
      if (v > best) { best = v; bp = pbase + p; }
    }
    u64 key = ((u64)__float_as_uint(best) << 32) | (u32)(0xFFFFFFFFu - (u32)bp);
    atomicMax(&gkey[gbase + tid], key);
  }
}

__global__ void k_scatter(const u64* __restrict__ gkey, int M, int* __restrict__ scat) {
  int g = blockIdx.x * blockDim.x + threadIdx.x;
  if (g >= M) return;
  u64 key = gkey[g];
  int p = (int)(0xFFFFFFFFu - (u32)(key & 0xFFFFFFFFull));
  atomicMax(&scat[p], g);  // duplicate idx_g: last (max g) wins, matching numpy sequential set
}

// Match assignment + pos CE + neg count + threefry bits + radix hist pass0 + per-block pos count.
__global__ void __launch_bounds__(256) k_match(const u64* __restrict__ rowkey,
    const int* __restrict__ scat, const int* __restrict__ gt_cls,
    const float* __restrict__ scores, const float* __restrict__ lse,
    int L, int C, int* __restrict__ matches, u32* __restrict__ u23,
    int* __restrict__ blockcnt, u32* __restrict__ hist0, State* st) {
  __shared__ int scnt[4];
  int tid = threadIdx.x;
  int i = blockIdx.x * 256 + tid;
  int m = -1;
  u32 ub = 0;
  if (i < L) {
    u64 rk = rowkey[i];
    float best = __uint_as_float((u32)(rk >> 32));
    int idxp = (int)(0xFFFFFFFFu - (u32)rk);
    if (best < F_LOWER) m = -2;
    else {
      int s = scat[i];
      m = (s >= 0) ? s : ((best >= F_UPPER) ? idxp : -1);
    }
    matches[i] = m;
    ub = threefry_bits((u32)i, (u32)(L >> 1)) >> 9;
    u23[i] = ub;
    if (m >= 0) {
      atomicAdd(&st->num_pos, 1);
      int lbl = gt_cls[m];
      float ce = lse[i] - scores[(size_t)i * C + lbl];
      atomicAdd(&st->sum_pos_ce, (double)ce);
    } else if (m == -2) {
      atomicAdd(&st->num_neg, 1);
      u64 key = ((u64)ub << 16) | (u32)i;
      atomicAdd(&hist0[(u32)(key >> 26)], 1u);
    }
  }
  u64 bal = __ballot(i < L && m >= 0);
  int lane = tid & 63, wid = tid >> 6;
  if (lane == 0) scnt[wid] = __popcll(bal);
  __syncthreads();
  if (tid == 0) blockcnt[blockIdx.x] = scnt[0] + scnt[1] + scnt[2] + scnt[3];
}

// Parallel index-ordered compaction of first MAX_POS positives.
__global__ void __launch_bounds__(256) k_pscat(const int* __restrict__ matches,
    const float4* __restrict__ pred, const float4* __restrict__ gt, int L,
    const int* __restrict__ blockcnt, float4* __restrict__ pp, float4* __restrict__ gp) {
  __shared__ int sb[256];
  __shared__ int wsum[4];
  int tid = threadIdx.x, bid = blockIdx.x;
  int lane = tid & 63, wid = tid >> 6;
  sb[tid] = blockcnt[tid];
  __syncthreads();
  for (int off = 1; off < 256; off <<= 1) {
    int v = (tid >= off) ? sb[tid - off] : 0;
    __syncthreads();
    sb[tid] += v;
    __syncthreads();
  }
  int bpref = (bid == 0) ? 0 : sb[bid - 1];
  if (bpref >= MAX_POS) return;  // whole block beyond cap
  int i = bid * 256 + tid;
  int m = (i < L) ? matches[i] : -1;
  int flag = (m >= 0) ? 1 : 0;
  int incl = flag;
#pragma unroll
  for (int off = 1; off < 64; off <<= 1) {
    int v = __shfl_up(incl, off, 64);
    if (lane >= off) incl += v;
  }
  if (lane == 63) wsum[wid] = incl;
  __syncthreads();
  int wbase = 0;
  for (int w = 0; w < wid; ++w) wbase += wsum[w];
  int rank = bpref + wbase + incl - flag;
  if (flag && rank < MAX_POS) { pp[rank] = pred[i]; gp[rank] = gt[m]; }
}

__global__ void k_hist(const int* __restrict__ matches, const u32* __restrict__ u23,
                       int L, int pass, State* st, u32* __restrict__ hist) {
  if (st->select_all) return;
  int i = blockIdx.x * blockDim.x + threadIdx.x;
  if (i >= L) return;
  if (matches[i] != -2) return;
  u64 key = ((u64)u23[i] << 16) | (u32)i;
  int shift = 26 - 13 * pass;
  if ((key >> (shift + 13)) != st->prefix) return;
  atomicAdd(&hist[(u32)((key >> shift) & 0x1FFFull)], 1u);
}

__global__ void __launch_bounds__(1024) k_scan(State* st, const u32* __restrict__ hist, int pass) {
  if (st->select_all) return;
  int tid = threadIdx.x;
  int k = (pass == 0) ? st->num_pos : st->sel_k;  // bg_num = round(num_pos*1.0) = num_pos
  if (pass == 0 && k >= st->num_neg) {
    if (tid == 0) { st->select_all = 1; st->thresh = ~0ull; }
    return;
  }
  int loc[8]; int tsum = 0;
#pragma unroll
  for (int r = 0; r < 8; ++r) { loc[r] = (int)hist[tid * 8 + r]; tsum += loc[r]; }
  __shared__ int sc[1024];
  sc[tid] = tsum;
  __syncthreads();
  for (int off = 1; off < 1024; off <<= 1) {
    int v = (tid >= off) ? sc[tid - off] : 0;
    __syncthreads();
    sc[tid] += v;
    __syncthreads();
  }
  int incl = sc[tid], excl = incl - tsum;
  if (k >= excl && k < incl) {
    int kk = k - excl; int d = 0;
#pragma unroll
    for (int r = 0; r < 8; ++r) {
      if (kk < loc[r]) { d = tid * 8 + r; break; }
      kk -= loc[r];
    }
    u64 np = (pass == 0) ? (u64)d : ((st->prefix << 13) | (u64)d);
    st->prefix = np;
    st->sel_k = kk;
    if (pass == 2) st->thresh = np;  // exact 39-bit key with rank == bg_num; select key < thresh
  }
}

__global__ void k_negsum(const int* __restrict__ matches, const u32* __restrict__ u23,
    const float* __restrict__ scores, const float* __restrict__ lse,
    int L, int C, State* st) {
  int i = blockIdx.x * blockDim.x + threadIdx.x;
  if (i >= L) return;
  if (matches[i] != -2) return;
  u64 key = ((u64)u23[i] << 16) | (u32)i;
  if (key < st->thresh) {
    float ce = lse[i] - scores[(size_t)i * C + (C - 1)];  // BACKGROUND = C-1 = 20
    atomicAdd(&st->sum_neg_ce, (double)ce);
  }
}

__global__ void __launch_bounds__(256) k_pairs(const float4* __restrict__ pp,
    const float4* __restrict__ gp, State* st) {
  __shared__ float4 sj[128];
  int tid = threadIdx.x;
  int n = st->num_pos; if (n > MAX_POS) n = MAX_POS;
  int jbase = blockIdx.y * 128;
  if (tid < 128) {
    int j = jbase + tid;
    sj[tid] = (j < n) ? pp[j] : make_float4(0.f, 0.f, 0.f, 0.f);
  }
  __syncthreads();
  int i = blockIdx.x * 256 + tid;
  double acc = 0.0;
  if (i < n) {
    float4 g = gp[i];
    int jend = n - jbase; if (jend > 128) jend = 128;
    for (int j = 0; j < jend; ++j) {
      float4 p = sj[j];
      acc += (double)sl1(p.x - g.x);
      acc += (double)sl1(p.y - g.y);
      acc += (double)sl1(p.z - g.z);
      acc += (double)sl1(p.w - g.w);
    }
  }
  for (int off = 32; off > 0; off >>= 1) acc += __shfl_down(acc, off, 64);
  __shared__ double wacc[4];
  int lane = tid & 63, wid = tid >> 6;
  if (lane == 0) wacc[wid] = acc;
  __syncthreads();
  if (tid == 0) atomicAdd(&st->bbox_sum, wacc[0] + wacc[1] + wacc[2] + wacc[3]);
}

__global__ void k_final(State* st, float* out) {
  int np = st->num_pos, nn = st->num_neg;
  int nsel = (np < nn) ? np : nn;  // min(bg_num, num_neg)
  double wsum = (double)(np + nsel);
  out[0] = (float)((st->sum_pos_ce + st->sum_neg_ce) / wsum);
  out[1] = (float)st->bbox_sum;
}

// ---------- launch ----------

extern "C" void kernel_launch(void* const* d_in, const int* in_sizes, int n_in,
                              void* d_out, int out_size, void* d_ws, size_t ws_size,
                              hipStream_t stream) {
  const float* rois   = (const float*)d_in[0];
  const float* scores = (const float*)d_in[1];
  const float* deltas = (const float*)d_in[2];
  const float* gtb    = (const float*)d_in[3];
  const int*   gtc    = (const int*)d_in[4];
  int L = in_sizes[0] / 5;
  int C = in_sizes[1] / L;
  int M = in_sizes[4];

  char* w = (char*)d_ws;
  State* st    = (State*)w;   w += 256;
  float4* pred = (float4*)w;  w += (size_t)L * 16;
  float* lse   = (float*)w;   w += (size_t)L * 4;
  u64* rowkey  = (u64*)w;     w += (size_t)L * 8;
  int* scat    = (int*)w;     w += (size_t)L * 4;
  int* matches = (int*)w;     w += (size_t)L * 4;
  u32* u23     = (u32*)w;     w += (size_t)L * 4;
  u64* gkey    = (u64*)w;     w += (size_t)M * 8;
  int* blockcnt= (int*)w;     w += 256 * 4;
  float4* pp   = (float4*)w;  w += (size_t)MAX_POS * 16;
  float4* gp   = (float4*)w;  w += (size_t)MAX_POS * 16;
  u32* hist    = (u32*)w;     w += 3 * 8192 * 4;

  int nb = (L + 255) / 256;
  int nhist = 3 * 8192;
  int initN = L > nhist ? L : nhist;
  if (M > initN) initN = M;

  k_init<<<(initN + 255) / 256, 256, 0, stream>>>(st, gkey, M, scat, rowkey, L, hist, nhist);
  k_roi<<<nb, 256, 0, stream>>>(rois, scores, deltas, L, C, pred, lse);
  dim3 ig((L + 127) / 128, (M + 255) / 256);
  k_iou<<<ig, 256, 0, stream>>>(pred, (const float4*)gtb, L, M, rowkey, gkey);
  k_scatter<<<(M + 255) / 256, 256, 0, stream>>>(gkey, M, scat);
  k_match<<<nb, 256, 0, stream>>>(rowkey, scat, gtc, scores, lse, L, C, matches, u23,
                                  blockcnt, hist, st);
  k_pscat<<<nb, 256, 0, stream>>>(matches, pred, (const float4*)gtb, L, blockcnt, pp, gp);
  k_scan<<<1, 1024, 0, stream>>>(st, hist, 0);
  for (int p = 1; p < 3; ++p) {
    k_hist<<<nb, 256, 0, stream>>>(matches, u23, L, p, st, hist + p * 8192);
    k_scan<<<1, 1024, 0, stream>>>(st, hist + p * 8192, p);
  }
  k_negsum<<<nb, 256, 0, stream>>>(matches, u23, scores, lse, L, C, st);
  dim3 pg((MAX_POS + 255) / 256, 16);
  k_pairs<<<pg, 256, 0, stream>>>(pp, gp, st);
  k_final<<<1, 1, 0, stream>>>(st, (float*)d_out);
}